// Round 1
// baseline (3254.197 us; speedup 1.0000x reference)
//
#include <hip/hip_runtime.h>
#include <hip/hip_bf16.h>

// ---------------------------------------------------------------------------
// VQ-VAE forward, fp32 direct kernels.
// Layout: NCHW everywhere (matches reference).
// Each conv thread computes ONE spatial position x CPT output channels held
// in registers; input taps loaded once and reused across channels; weight
// indices are wave-uniform -> scalar loads.
// ---------------------------------------------------------------------------

template<int CIN, int CPT, int K, int STRIDE, int PAD,
         bool RELU_IN, bool HAS_BIAS, bool RESID, bool RELU_OUT>
__global__ __launch_bounds__(256) void conv_direct(
    const float* __restrict__ in, const float* __restrict__ w,
    const float* __restrict__ bias, const float* __restrict__ resid,
    float* __restrict__ out,
    int B, int H, int W, int OH, int OW, int COUT_TOTAL)
{
    const int gid = blockIdx.x * 256 + threadIdx.x;
    const int total = B * OH * OW;
    if (gid >= total) return;
    const int ow = gid % OW;
    const int t1 = gid / OW;
    const int oh = t1 % OH;
    const int b  = t1 / OH;
    const int co0 = blockIdx.y * CPT;

    float acc[CPT];
#pragma unroll
    for (int c = 0; c < CPT; c++) acc[c] = HAS_BIAS ? bias[co0 + c] : 0.0f;

    const float* __restrict__ inb = in + (size_t)b * CIN * H * W;

#pragma unroll 1
    for (int ci = 0; ci < CIN; ci++) {
        const float* __restrict__ inc = inb + (size_t)ci * H * W;
        const float* __restrict__ wci = w + ((size_t)co0 * CIN + ci) * (K * K);
#pragma unroll
        for (int kh = 0; kh < K; kh++) {
            const int ih = oh * STRIDE - PAD + kh;
            const bool okh = (ih >= 0) && (ih < H);
#pragma unroll
            for (int kw = 0; kw < K; kw++) {
                const int iw = ow * STRIDE - PAD + kw;
                const bool ok = okh && (iw >= 0) && (iw < W);
                float v = ok ? inc[(size_t)ih * W + iw] : 0.0f;
                if (RELU_IN) v = fmaxf(v, 0.0f);
#pragma unroll
                for (int c = 0; c < CPT; c++)
                    acc[c] = fmaf(v, wci[(size_t)c * CIN * K * K + kh * K + kw], acc[c]);
            }
        }
    }

    const size_t obase = (((size_t)b * COUT_TOTAL + co0) * OH + oh) * OW + ow;
    const size_t cstride = (size_t)OH * OW;
#pragma unroll
    for (int c = 0; c < CPT; c++) {
        float r = acc[c];
        if (RESID) r += resid[obase + (size_t)c * cstride];
        if (RELU_OUT) r = fmaxf(r, 0.0f);
        out[obase + (size_t)c * cstride] = r;
    }
}

// Transposed conv 4x4 stride 2 pad 1 (PyTorch ConvTranspose2d semantics):
// out[b,co,oh,ow] = bias[co] + sum_{ci,kh,kw: oh=2*ih-1+kh, ow=2*iw-1+kw}
//                   in[b,ci,ih,iw] * w[ci,co,kh,kw]
// blockIdx.y encodes the output parity class (oh&1, ow&1) so the (kh,kw)
// tap set is uniform across the block (scalar weight loads).
template<int CIN, int COUT, bool RELU_OUT>
__global__ __launch_bounds__(256) void convt4x4s2(
    const float* __restrict__ in, const float* __restrict__ w,
    const float* __restrict__ bias, float* __restrict__ out,
    int B, int IH, int IW)
{
    const int OH = IH * 2, OW = IW * 2;
    const int tilesX = IW / 64;           // IW is 64 or 128
    const int bx = blockIdx.x % tilesX;
    const int by = blockIdx.x / tilesX;
    const int j = bx * 64 + threadIdx.x;  // half-res ow coord
    const int i = by * 4 + threadIdx.y;   // half-res oh coord
    const int par = blockIdx.y;
    const int pr = par >> 1, pc = par & 1;
    const int b = blockIdx.z;
    const int oh = 2 * i + pr, ow = 2 * j + pc;

    float acc[COUT];
#pragma unroll
    for (int c = 0; c < COUT; c++) acc[c] = bias[c];

    const float* __restrict__ inb = in + (size_t)b * CIN * IH * IW;

#pragma unroll
    for (int ta = 0; ta < 2; ta++) {
        const int kh = (1 - pr) + 2 * ta;
        const int ih = (oh + 1 - kh) >> 1;
        const bool okh = (ih >= 0) && (ih < IH);
#pragma unroll
        for (int tb = 0; tb < 2; tb++) {
            const int kw = (1 - pc) + 2 * tb;
            const int iw = (ow + 1 - kw) >> 1;
            if (!(okh && iw >= 0 && iw < IW)) continue;
            const float* __restrict__ wp = w + (size_t)(kh * 4 + kw);
#pragma unroll 1
            for (int ci = 0; ci < CIN; ci++) {
                const float v = inb[((size_t)ci * IH + ih) * IW + iw];
#pragma unroll
                for (int c = 0; c < COUT; c++)
                    acc[c] = fmaf(v, wp[(size_t)(ci * COUT + c) * 16], acc[c]);
            }
        }
    }

    const size_t ob = (((size_t)b * COUT) * OH + oh) * OW + ow;
    const size_t cstride = (size_t)OH * OW;
#pragma unroll
    for (int c = 0; c < COUT; c++) {
        float r = acc[c];
        if (RELU_OUT) r = fmaxf(r, 0.0f);
        out[ob + (size_t)c * cstride] = r;
    }
}

// Vector quantization: one thread per point (B*HW points, D=64, K=512).
// d = ||x||^2 - 2 x.e + ||e||^2 (matches reference formula); strict < keeps
// the first minimizing index (jnp.argmin semantics).
__global__ __launch_bounds__(256) void vq_kernel(
    const float* __restrict__ h,   // (B,64,HW)
    const float* __restrict__ cb,  // (512,64)
    float* __restrict__ q,         // (B,64,HW)
    int B, int HW)
{
    __shared__ float ee[512];
    for (int k = threadIdx.x; k < 512; k += 256) {
        const float* __restrict__ cp = cb + (size_t)k * 64;
        float s = 0.0f;
#pragma unroll
        for (int i = 0; i < 64; i++) s = fmaf(cp[i], cp[i], s);
        ee[k] = s;
    }
    __syncthreads();

    const int gid = blockIdx.x * 256 + threadIdx.x;
    const int total = B * HW;
    if (gid >= total) return;
    const int hw = gid % HW;
    const int b  = gid / HW;

    const float* __restrict__ hp = h + (size_t)b * 64 * HW + hw;
    float x[64];
#pragma unroll
    for (int i = 0; i < 64; i++) x[i] = hp[(size_t)i * HW];
    float xx = 0.0f;
#pragma unroll
    for (int i = 0; i < 64; i++) xx = fmaf(x[i], x[i], xx);

    float best = 3.402823466e+38f;
    int bidx = 0;
#pragma unroll 1
    for (int k = 0; k < 512; k++) {
        const float* __restrict__ cp = cb + (size_t)k * 64;
        float dot = 0.0f;
#pragma unroll
        for (int i = 0; i < 64; i++) dot = fmaf(x[i], cp[i], dot);
        const float d = xx - 2.0f * dot + ee[k];
        if (d < best) { best = d; bidx = k; }
    }

    const float* __restrict__ cp = cb + (size_t)bidx * 64;
    float* __restrict__ qp = q + (size_t)b * 64 * HW + hw;
#pragma unroll
    for (int i = 0; i < 64; i++) qp[(size_t)i * HW] = cp[i];
}

extern "C" void kernel_launch(void* const* d_in, const int* in_sizes, int n_in,
                              void* d_out, int out_size, void* d_ws, size_t ws_size,
                              hipStream_t stream) {
    const float* x      = (const float*)d_in[0];
    const float* w_e1   = (const float*)d_in[1];
    const float* b_e1   = (const float*)d_in[2];
    const float* w_e2   = (const float*)d_in[3];
    const float* b_e2   = (const float*)d_in[4];
    const float* w_er1a = (const float*)d_in[5];
    const float* w_er1b = (const float*)d_in[6];
    const float* w_er2a = (const float*)d_in[7];
    const float* w_er2b = (const float*)d_in[8];
    const float* w_pre  = (const float*)d_in[9];
    const float* b_pre  = (const float*)d_in[10];
    const float* cbk    = (const float*)d_in[11];
    const float* w_d1   = (const float*)d_in[12];
    const float* b_d1   = (const float*)d_in[13];
    const float* w_dr1a = (const float*)d_in[14];
    const float* w_dr1b = (const float*)d_in[15];
    const float* w_dr2a = (const float*)d_in[16];
    const float* w_dr2b = (const float*)d_in[17];
    const float* w_t1   = (const float*)d_in[18];
    const float* b_t1   = (const float*)d_in[19];
    const float* w_t2   = (const float*)d_in[20];
    const float* b_t2   = (const float*)d_in[21];
    float* out = (float*)d_out;

    // Workspace layout (floats)
    float* A  = (float*)d_ws;            // (32,32,128,128) = 16777216
    float* Bb = A  + 16777216;           // (32,64,64,64)   = 8388608
    float* C  = Bb + 8388608;            // (32,32,64,64)   = 4194304
    float* D  = C  + 4194304;            // (32,64,64,64)   = 8388608

    const dim3 blk(256);

    // Encoder
    // e1: (32,1,256,256) -> relu -> A (32,32,128,128)
    conv_direct<1, 32, 4, 2, 1, false, true, false, true>
        <<<dim3(32 * 128 * 128 / 256, 1), blk, 0, stream>>>(
            x, w_e1, b_e1, nullptr, A, 32, 256, 256, 128, 128, 32);
    // e2: A -> Bb (32,64,64,64), no relu
    conv_direct<32, 32, 4, 2, 1, false, true, false, false>
        <<<dim3(32 * 64 * 64 / 256, 2), blk, 0, stream>>>(
            A, w_e2, b_e2, nullptr, Bb, 32, 128, 128, 64, 64, 64);
    // er1: C = conv3x3(relu(Bb)); Bb = Bb + conv1x1(relu(C))
    conv_direct<64, 32, 3, 1, 1, true, false, false, false>
        <<<dim3(32 * 64 * 64 / 256, 1), blk, 0, stream>>>(
            Bb, w_er1a, nullptr, nullptr, C, 32, 64, 64, 64, 64, 32);
    conv_direct<32, 64, 1, 1, 0, true, false, true, false>
        <<<dim3(32 * 64 * 64 / 256, 1), blk, 0, stream>>>(
            C, w_er1b, nullptr, Bb, Bb, 32, 64, 64, 64, 64, 64);
    // er2
    conv_direct<64, 32, 3, 1, 1, true, false, false, false>
        <<<dim3(32 * 64 * 64 / 256, 1), blk, 0, stream>>>(
            Bb, w_er2a, nullptr, nullptr, C, 32, 64, 64, 64, 64, 32);
    conv_direct<32, 64, 1, 1, 0, true, false, true, false>
        <<<dim3(32 * 64 * 64 / 256, 1), blk, 0, stream>>>(
            C, w_er2b, nullptr, Bb, Bb, 32, 64, 64, 64, 64, 64);
    // pre-VQ 1x1: Bb -> D
    conv_direct<64, 64, 1, 1, 0, false, true, false, false>
        <<<dim3(32 * 64 * 64 / 256, 1), blk, 0, stream>>>(
            Bb, w_pre, b_pre, nullptr, D, 32, 64, 64, 64, 64, 64);
    // VQ: D -> Bb (quantized)
    vq_kernel<<<dim3(32 * 4096 / 256), blk, 0, stream>>>(D, cbk, Bb, 32, 4096);
    // Decoder
    // d1: Bb -> D, 3x3 + bias
    conv_direct<64, 32, 3, 1, 1, false, true, false, false>
        <<<dim3(32 * 64 * 64 / 256, 2), blk, 0, stream>>>(
            Bb, w_d1, b_d1, nullptr, D, 32, 64, 64, 64, 64, 64);
    // dr1
    conv_direct<64, 32, 3, 1, 1, true, false, false, false>
        <<<dim3(32 * 64 * 64 / 256, 1), blk, 0, stream>>>(
            D, w_dr1a, nullptr, nullptr, C, 32, 64, 64, 64, 64, 32);
    conv_direct<32, 64, 1, 1, 0, true, false, true, false>
        <<<dim3(32 * 64 * 64 / 256, 1), blk, 0, stream>>>(
            C, w_dr1b, nullptr, D, D, 32, 64, 64, 64, 64, 64);
    // dr2
    conv_direct<64, 32, 3, 1, 1, true, false, false, false>
        <<<dim3(32 * 64 * 64 / 256, 1), blk, 0, stream>>>(
            D, w_dr2a, nullptr, nullptr, C, 32, 64, 64, 64, 64, 32);
    conv_direct<32, 64, 1, 1, 0, true, false, true, false>
        <<<dim3(32 * 64 * 64 / 256, 1), blk, 0, stream>>>(
            C, w_dr2b, nullptr, D, D, 32, 64, 64, 64, 64, 64);
    // t1: D -> A (32,32,128,128), relu
    convt4x4s2<64, 32, true>
        <<<dim3(16, 4, 32), dim3(64, 4, 1), 0, stream>>>(
            D, w_t1, b_t1, A, 32, 64, 64);
    // t2: A -> out (32,1,256,256)
    convt4x4s2<32, 1, false>
        <<<dim3(64, 4, 32), dim3(64, 4, 1), 0, stream>>>(
            A, w_t2, b_t2, out, 32, 128, 128);
}

// Round 2
// 2703.929 us; speedup vs baseline: 1.2035x; 1.2035x over previous
//
#include <hip/hip_runtime.h>
#include <hip/hip_bf16.h>

// ---------------------------------------------------------------------------
// VQ-VAE forward, fp32 direct kernels. NCHW layout.
// R2: fix latency-boundness — unroll ci loops for load ILP; dedicated 2x2-quad
// kernel for the final transposed conv (COUT=1 was 1 load : 1 FMA serial).
// ---------------------------------------------------------------------------

template<int CIN, int CPT, int K, int STRIDE, int PAD,
         bool RELU_IN, bool HAS_BIAS, bool RESID, bool RELU_OUT>
__global__ __launch_bounds__(256) void conv_direct(
    const float* __restrict__ in, const float* __restrict__ w,
    const float* __restrict__ bias, const float* __restrict__ resid,
    float* __restrict__ out,
    int B, int H, int W, int OH, int OW, int COUT_TOTAL)
{
    const int gid = blockIdx.x * 256 + threadIdx.x;
    const int total = B * OH * OW;
    if (gid >= total) return;
    const int ow = gid % OW;
    const int t1 = gid / OW;
    const int oh = t1 % OH;
    const int b  = t1 / OH;
    const int co0 = blockIdx.y * CPT;

    float acc[CPT];
#pragma unroll
    for (int c = 0; c < CPT; c++) acc[c] = HAS_BIAS ? bias[co0 + c] : 0.0f;

    const float* __restrict__ inb = in + (size_t)b * CIN * H * W;

#pragma unroll 2
    for (int ci = 0; ci < CIN; ci++) {
        const float* __restrict__ inc = inb + (size_t)ci * H * W;
        const float* __restrict__ wci = w + ((size_t)co0 * CIN + ci) * (K * K);
        // load all taps for this ci first (independent loads -> ILP)
        float v[K * K];
#pragma unroll
        for (int kh = 0; kh < K; kh++) {
            const int ih = oh * STRIDE - PAD + kh;
            const bool okh = (ih >= 0) && (ih < H);
#pragma unroll
            for (int kw = 0; kw < K; kw++) {
                const int iw = ow * STRIDE - PAD + kw;
                const bool ok = okh && (iw >= 0) && (iw < W);
                float t = ok ? inc[(size_t)ih * W + iw] : 0.0f;
                if (RELU_IN) t = fmaxf(t, 0.0f);
                v[kh * K + kw] = t;
            }
        }
#pragma unroll
        for (int kk = 0; kk < K * K; kk++) {
#pragma unroll
            for (int c = 0; c < CPT; c++)
                acc[c] = fmaf(v[kk], wci[(size_t)c * CIN * K * K + kk], acc[c]);
        }
    }

    const size_t obase = (((size_t)b * COUT_TOTAL + co0) * OH + oh) * OW + ow;
    const size_t cstride = (size_t)OH * OW;
#pragma unroll
    for (int c = 0; c < CPT; c++) {
        float r = acc[c];
        if (RESID) r += resid[obase + (size_t)c * cstride];
        if (RELU_OUT) r = fmaxf(r, 0.0f);
        out[obase + (size_t)c * cstride] = r;
    }
}

// Transposed conv 4x4 stride 2 pad 1, parity-class blocks (wave-uniform taps).
template<int CIN, int COUT, bool RELU_OUT>
__global__ __launch_bounds__(256) void convt4x4s2(
    const float* __restrict__ in, const float* __restrict__ w,
    const float* __restrict__ bias, float* __restrict__ out,
    int B, int IH, int IW)
{
    const int OH = IH * 2, OW = IW * 2;
    const int tilesX = IW / 64;
    const int bx = blockIdx.x % tilesX;
    const int by = blockIdx.x / tilesX;
    const int j = bx * 64 + threadIdx.x;
    const int i = by * 4 + threadIdx.y;
    const int par = blockIdx.y;
    const int pr = par >> 1, pc = par & 1;
    const int b = blockIdx.z;
    const int oh = 2 * i + pr, ow = 2 * j + pc;

    float acc[COUT];
#pragma unroll
    for (int c = 0; c < COUT; c++) acc[c] = bias[c];

    const float* __restrict__ inb = in + (size_t)b * CIN * IH * IW;

#pragma unroll
    for (int ta = 0; ta < 2; ta++) {
        const int kh = (1 - pr) + 2 * ta;
        const int ih = (oh + 1 - kh) >> 1;
        const bool okh = (ih >= 0) && (ih < IH);
#pragma unroll
        for (int tb = 0; tb < 2; tb++) {
            const int kw = (1 - pc) + 2 * tb;
            const int iw = (ow + 1 - kw) >> 1;
            if (!(okh && iw >= 0 && iw < IW)) continue;
            const float* __restrict__ wp = w + (size_t)(kh * 4 + kw);
#pragma unroll 4
            for (int ci = 0; ci < CIN; ci++) {
                const float v = inb[((size_t)ci * IH + ih) * IW + iw];
#pragma unroll
                for (int c = 0; c < COUT; c++)
                    acc[c] = fmaf(v, wp[(size_t)(ci * COUT + c) * 16], acc[c]);
            }
        }
    }

    const size_t ob = (((size_t)b * COUT) * OH + oh) * OW + ow;
    const size_t cstride = (size_t)OH * OW;
#pragma unroll
    for (int c = 0; c < COUT; c++) {
        float r = acc[c];
        if (RELU_OUT) r = fmaxf(r, 0.0f);
        out[ob + (size_t)c * cstride] = r;
    }
}

// Final transposed conv (CIN=32 -> COUT=1): one thread per half-res position
// computes the whole 2x2 output quad from its 3x3 input neighborhood.
// 288 independent loads : 512 FMAs per thread; float2 coalesced stores.
__global__ __launch_bounds__(256) void convt2_quad(
    const float* __restrict__ in,  // (B,32,128,128)
    const float* __restrict__ w,   // (32,1,4,4)
    const float* __restrict__ bias,
    float* __restrict__ out,       // (B,1,256,256)
    int B)
{
    const int IH = 128, IW = 128, CIN = 32, OW = 256;
    const int j = threadIdx.x & 127;
    const int i = (blockIdx.x << 1) + (threadIdx.x >> 7);
    const int b = blockIdx.y;

    const float* __restrict__ inb = in + (size_t)b * CIN * IH * IW;
    const float bz = bias[0];
    float a00 = bz, a01 = bz, a10 = bz, a11 = bz;

    const bool okm = (i > 0);
    const bool okp = (i < IH - 1);
    const bool olm = (j > 0);
    const bool olp = (j < IW - 1);

#pragma unroll 4
    for (int ci = 0; ci < CIN; ci++) {
        const float* __restrict__ p = inb + ((size_t)ci * IH + i) * IW + j;
        const float* __restrict__ wp = w + ci * 16;
        const float vmm = (okm && olm) ? p[-IW - 1] : 0.f;
        const float vm0 = okm ? p[-IW] : 0.f;
        const float vmp = (okm && olp) ? p[-IW + 1] : 0.f;
        const float v0m = olm ? p[-1] : 0.f;
        const float v00 = p[0];
        const float v0p = olp ? p[1] : 0.f;
        const float vpm = (okp && olm) ? p[IW - 1] : 0.f;
        const float vp0 = okp ? p[IW] : 0.f;
        const float vpp = (okp && olp) ? p[IW + 1] : 0.f;
        // oh=2i+pr: pr=0 -> kh{1:row i, 3:row i-1}; pr=1 -> kh{0:row i+1, 2:row i}
        // ow=2j+pc: pc=0 -> kw{1:col j, 3:col j-1}; pc=1 -> kw{0:col j+1, 2:col j}
        a00 = fmaf(v00, wp[1 * 4 + 1], a00);
        a00 = fmaf(v0m, wp[1 * 4 + 3], a00);
        a00 = fmaf(vm0, wp[3 * 4 + 1], a00);
        a00 = fmaf(vmm, wp[3 * 4 + 3], a00);
        a01 = fmaf(v0p, wp[1 * 4 + 0], a01);
        a01 = fmaf(v00, wp[1 * 4 + 2], a01);
        a01 = fmaf(vmp, wp[3 * 4 + 0], a01);
        a01 = fmaf(vm0, wp[3 * 4 + 2], a01);
        a10 = fmaf(vp0, wp[0 * 4 + 1], a10);
        a10 = fmaf(vpm, wp[0 * 4 + 3], a10);
        a10 = fmaf(v00, wp[2 * 4 + 1], a10);
        a10 = fmaf(v0m, wp[2 * 4 + 3], a10);
        a11 = fmaf(vpp, wp[0 * 4 + 0], a11);
        a11 = fmaf(vp0, wp[0 * 4 + 2], a11);
        a11 = fmaf(v0p, wp[2 * 4 + 0], a11);
        a11 = fmaf(v00, wp[2 * 4 + 2], a11);
    }

    float* __restrict__ outb = out + (size_t)b * 256 * 256;
    float2 r0 = make_float2(a00, a01);
    float2 r1 = make_float2(a10, a11);
    ((float2*)(outb + (size_t)(2 * i) * OW))[j] = r0;
    ((float2*)(outb + (size_t)(2 * i + 1) * OW))[j] = r1;
}

// Vector quantization: one thread per point (B*HW points, D=64, K=512).
__global__ __launch_bounds__(256) void vq_kernel(
    const float* __restrict__ h,   // (B,64,HW)
    const float* __restrict__ cb,  // (512,64)
    float* __restrict__ q,         // (B,64,HW)
    int B, int HW)
{
    __shared__ float ee[512];
    for (int k = threadIdx.x; k < 512; k += 256) {
        const float* __restrict__ cp = cb + (size_t)k * 64;
        float s = 0.0f;
#pragma unroll
        for (int i = 0; i < 64; i++) s = fmaf(cp[i], cp[i], s);
        ee[k] = s;
    }
    __syncthreads();

    const int gid = blockIdx.x * 256 + threadIdx.x;
    const int total = B * HW;
    if (gid >= total) return;
    const int hw = gid % HW;
    const int b  = gid / HW;

    const float* __restrict__ hp = h + (size_t)b * 64 * HW + hw;
    float x[64];
#pragma unroll
    for (int i = 0; i < 64; i++) x[i] = hp[(size_t)i * HW];
    float xx = 0.0f;
#pragma unroll
    for (int i = 0; i < 64; i++) xx = fmaf(x[i], x[i], xx);

    float best = 3.402823466e+38f;
    int bidx = 0;
#pragma unroll 2
    for (int k = 0; k < 512; k++) {
        const float* __restrict__ cp = cb + (size_t)k * 64;
        float dot = 0.0f;
#pragma unroll
        for (int i = 0; i < 64; i++) dot = fmaf(x[i], cp[i], dot);
        const float d = xx - 2.0f * dot + ee[k];
        if (d < best) { best = d; bidx = k; }
    }

    const float* __restrict__ cp = cb + (size_t)bidx * 64;
    float* __restrict__ qp = q + (size_t)b * 64 * HW + hw;
#pragma unroll
    for (int i = 0; i < 64; i++) qp[(size_t)i * HW] = cp[i];
}

extern "C" void kernel_launch(void* const* d_in, const int* in_sizes, int n_in,
                              void* d_out, int out_size, void* d_ws, size_t ws_size,
                              hipStream_t stream) {
    const float* x      = (const float*)d_in[0];
    const float* w_e1   = (const float*)d_in[1];
    const float* b_e1   = (const float*)d_in[2];
    const float* w_e2   = (const float*)d_in[3];
    const float* b_e2   = (const float*)d_in[4];
    const float* w_er1a = (const float*)d_in[5];
    const float* w_er1b = (const float*)d_in[6];
    const float* w_er2a = (const float*)d_in[7];
    const float* w_er2b = (const float*)d_in[8];
    const float* w_pre  = (const float*)d_in[9];
    const float* b_pre  = (const float*)d_in[10];
    const float* cbk    = (const float*)d_in[11];
    const float* w_d1   = (const float*)d_in[12];
    const float* b_d1   = (const float*)d_in[13];
    const float* w_dr1a = (const float*)d_in[14];
    const float* w_dr1b = (const float*)d_in[15];
    const float* w_dr2a = (const float*)d_in[16];
    const float* w_dr2b = (const float*)d_in[17];
    const float* w_t1   = (const float*)d_in[18];
    const float* b_t1   = (const float*)d_in[19];
    const float* w_t2   = (const float*)d_in[20];
    const float* b_t2   = (const float*)d_in[21];
    float* out = (float*)d_out;

    float* A  = (float*)d_ws;            // (32,32,128,128) = 16777216
    float* Bb = A  + 16777216;           // (32,64,64,64)   = 8388608
    float* C  = Bb + 8388608;            // (32,32,64,64)   = 4194304
    float* D  = C  + 4194304;            // (32,64,64,64)   = 8388608

    const dim3 blk(256);

    // Encoder
    conv_direct<1, 32, 4, 2, 1, false, true, false, true>
        <<<dim3(32 * 128 * 128 / 256, 1), blk, 0, stream>>>(
            x, w_e1, b_e1, nullptr, A, 32, 256, 256, 128, 128, 32);
    conv_direct<32, 32, 4, 2, 1, false, true, false, false>
        <<<dim3(32 * 64 * 64 / 256, 2), blk, 0, stream>>>(
            A, w_e2, b_e2, nullptr, Bb, 32, 128, 128, 64, 64, 64);
    conv_direct<64, 32, 3, 1, 1, true, false, false, false>
        <<<dim3(32 * 64 * 64 / 256, 1), blk, 0, stream>>>(
            Bb, w_er1a, nullptr, nullptr, C, 32, 64, 64, 64, 64, 32);
    conv_direct<32, 64, 1, 1, 0, true, false, true, false>
        <<<dim3(32 * 64 * 64 / 256, 1), blk, 0, stream>>>(
            C, w_er1b, nullptr, Bb, Bb, 32, 64, 64, 64, 64, 64);
    conv_direct<64, 32, 3, 1, 1, true, false, false, false>
        <<<dim3(32 * 64 * 64 / 256, 1), blk, 0, stream>>>(
            Bb, w_er2a, nullptr, nullptr, C, 32, 64, 64, 64, 64, 32);
    conv_direct<32, 64, 1, 1, 0, true, false, true, false>
        <<<dim3(32 * 64 * 64 / 256, 1), blk, 0, stream>>>(
            C, w_er2b, nullptr, Bb, Bb, 32, 64, 64, 64, 64, 64);
    conv_direct<64, 64, 1, 1, 0, false, true, false, false>
        <<<dim3(32 * 64 * 64 / 256, 1), blk, 0, stream>>>(
            Bb, w_pre, b_pre, nullptr, D, 32, 64, 64, 64, 64, 64);
    // VQ
    vq_kernel<<<dim3(32 * 4096 / 256), blk, 0, stream>>>(D, cbk, Bb, 32, 4096);
    // Decoder
    conv_direct<64, 32, 3, 1, 1, false, true, false, false>
        <<<dim3(32 * 64 * 64 / 256, 2), blk, 0, stream>>>(
            Bb, w_d1, b_d1, nullptr, D, 32, 64, 64, 64, 64, 64);
    conv_direct<64, 32, 3, 1, 1, true, false, false, false>
        <<<dim3(32 * 64 * 64 / 256, 1), blk, 0, stream>>>(
            D, w_dr1a, nullptr, nullptr, C, 32, 64, 64, 64, 64, 32);
    conv_direct<32, 64, 1, 1, 0, true, false, true, false>
        <<<dim3(32 * 64 * 64 / 256, 1), blk, 0, stream>>>(
            C, w_dr1b, nullptr, D, D, 32, 64, 64, 64, 64, 64);
    conv_direct<64, 32, 3, 1, 1, true, false, false, false>
        <<<dim3(32 * 64 * 64 / 256, 1), blk, 0, stream>>>(
            D, w_dr2a, nullptr, nullptr, C, 32, 64, 64, 64, 64, 32);
    conv_direct<32, 64, 1, 1, 0, true, false, true, false>
        <<<dim3(32 * 64 * 64 / 256, 1), blk, 0, stream>>>(
            C, w_dr2b, nullptr, D, D, 32, 64, 64, 64, 64, 64);
    // t1: D -> A (32,32,128,128), relu
    convt4x4s2<64, 32, true>
        <<<dim3(16, 4, 32), dim3(64, 4, 1), 0, stream>>>(
            D, w_t1, b_t1, A, 32, 64, 64);
    // t2: A -> out (32,1,256,256)
    convt2_quad<<<dim3(64, 32), blk, 0, stream>>>(A, w_t2, b_t2, out, 32);
}

// Round 4
// 2107.841 us; speedup vs baseline: 1.5439x; 1.2828x over previous
//
#include <hip/hip_runtime.h>
#include <hip/hip_bf16.h>

// ---------------------------------------------------------------------------
// VQ-VAE forward, fp32 direct kernels. NCHW layout.
// R4: R3 (cout-innermost weight repack) + revert VQ dot product to the R2
// sequential FMA chain — the 4-partial-sum version flipped argmin for some
// points (codebook spacing ~2/512; 1-ulp distance changes matter).
// DO NOT change FMA accumulation order anywhere upstream of the VQ argmin.
// ---------------------------------------------------------------------------

// dst[(ci*KK+kk)*COUT+co] = src[(co*CIN+ci)*KK+kk]
__global__ __launch_bounds__(256) void repack_w(
    const float* __restrict__ src, float* __restrict__ dst,
    int COUT, int CIN, int KK)
{
    const int n = COUT * CIN * KK;
    const int idx = blockIdx.x * 256 + threadIdx.x;
    if (idx >= n) return;
    const int co = idx % COUT;
    const int t  = idx / COUT;
    const int kk = t % KK;
    const int ci = t / KK;
    dst[idx] = src[(co * CIN + ci) * KK + kk];
}

// t1 weights (64,32,4,4) [ci][co][kh][kw] -> dst[par][ci][tap][co]
// par=pr*2+pc, tap=ta*2+tb, kh=(1-pr)+2*ta, kw=(1-pc)+2*tb
__global__ __launch_bounds__(256) void repack_t1(
    const float* __restrict__ src, float* __restrict__ dst)
{
    const int idx = blockIdx.x * 256 + threadIdx.x;
    if (idx >= 32768) return;
    const int co  = idx & 31;
    const int tap = (idx >> 5) & 3;
    const int ci  = (idx >> 7) & 63;
    const int par = idx >> 13;
    const int pr = par >> 1, pc = par & 1;
    const int ta = tap >> 1, tb = tap & 1;
    const int kh = (1 - pr) + 2 * ta, kw = (1 - pc) + 2 * tb;
    dst[idx] = src[((ci * 32 + co) * 4 + kh) * 4 + kw];
}

template<int CIN, int CTOT, int CPT, int K, int STRIDE, int PAD,
         bool RELU_IN, bool HAS_BIAS, bool RESID, bool RELU_OUT>
__global__ __launch_bounds__(256) void conv_direct(
    const float* __restrict__ in, const float* __restrict__ wr,
    const float* __restrict__ bias, const float* __restrict__ resid,
    float* __restrict__ out,
    int B, int H, int W, int OH, int OW)
{
    const int gid = blockIdx.x * 256 + threadIdx.x;
    const int total = B * OH * OW;
    if (gid >= total) return;
    const int ow = gid % OW;
    const int t1 = gid / OW;
    const int oh = t1 % OH;
    const int b  = t1 / OH;
    const int co0 = blockIdx.y * CPT;
    const int KK = K * K;

    float acc[CPT];
#pragma unroll
    for (int c = 0; c < CPT; c++) acc[c] = HAS_BIAS ? bias[co0 + c] : 0.0f;

    const float* __restrict__ inb = in + (size_t)b * CIN * H * W;

#pragma unroll 2
    for (int ci = 0; ci < CIN; ci++) {
        const float* __restrict__ inc = inb + (size_t)ci * H * W;
        float v[K * K];
#pragma unroll
        for (int kh = 0; kh < K; kh++) {
            const int ih = oh * STRIDE - PAD + kh;
            const bool okh = (ih >= 0) && (ih < H);
#pragma unroll
            for (int kw = 0; kw < K; kw++) {
                const int iw = ow * STRIDE - PAD + kw;
                const bool ok = okh && (iw >= 0) && (iw < W);
                float t = ok ? inc[(size_t)ih * W + iw] : 0.0f;
                if (RELU_IN) t = fmaxf(t, 0.0f);
                v[kh * K + kw] = t;
            }
        }
        const float* __restrict__ wc = wr + ((size_t)ci * KK) * CTOT + co0;
#pragma unroll
        for (int kk = 0; kk < KK; kk++) {
#pragma unroll
            for (int c = 0; c < CPT; c++)
                acc[c] = fmaf(v[kk], wc[(size_t)kk * CTOT + c], acc[c]);
        }
    }

    const size_t obase = (((size_t)b * CTOT + co0) * OH + oh) * OW + ow;
    const size_t cstride = (size_t)OH * OW;
#pragma unroll
    for (int c = 0; c < CPT; c++) {
        float r = acc[c];
        if (RESID) r += resid[obase + (size_t)c * cstride];
        if (RELU_OUT) r = fmaxf(r, 0.0f);
        out[obase + (size_t)c * cstride] = r;
    }
}

// Transposed conv 4x4 s2 p1, parity-class blocks; all 4 taps fused in the
// ci loop; weights repacked [par][ci][tap][cout] (contiguous 128/ci).
template<int CIN, int COUT, bool RELU_OUT>
__global__ __launch_bounds__(256) void convt4x4s2(
    const float* __restrict__ in, const float* __restrict__ wr,
    const float* __restrict__ bias, float* __restrict__ out,
    int B, int IH, int IW)
{
    const int OH = IH * 2, OW = IW * 2;
    const int j = threadIdx.x;
    const int i = blockIdx.x * 4 + threadIdx.y;
    const int par = blockIdx.y;
    const int pr = par >> 1, pc = par & 1;
    const int b = blockIdx.z;
    const int oh = 2 * i + pr, ow = 2 * j + pc;

    float acc[COUT];
#pragma unroll
    for (int c = 0; c < COUT; c++) acc[c] = bias[c];

    int ihs[2], iws[2];
    bool okh[2], okw[2];
#pragma unroll
    for (int ta = 0; ta < 2; ta++) {
        const int kh = (1 - pr) + 2 * ta;
        ihs[ta] = (oh + 1 - kh) >> 1;
        okh[ta] = (ihs[ta] >= 0) && (ihs[ta] < IH);
        const int kw = (1 - pc) + 2 * ta;
        iws[ta] = (ow + 1 - kw) >> 1;
        okw[ta] = (iws[ta] >= 0) && (iws[ta] < IW);
    }

    const float* __restrict__ inb = in + (size_t)b * CIN * IH * IW;
    const float* __restrict__ wpar = wr + (size_t)par * CIN * 4 * COUT;

#pragma unroll 2
    for (int ci = 0; ci < CIN; ci++) {
        const float* __restrict__ pc_ = inb + (size_t)ci * IH * IW;
        float v[4];
#pragma unroll
        for (int ta = 0; ta < 2; ta++)
#pragma unroll
            for (int tb = 0; tb < 2; tb++)
                v[ta * 2 + tb] = (okh[ta] && okw[tb])
                    ? pc_[(size_t)ihs[ta] * IW + iws[tb]] : 0.0f;
        const float* __restrict__ wc = wpar + (size_t)ci * 4 * COUT;
#pragma unroll
        for (int tap = 0; tap < 4; tap++)
#pragma unroll
            for (int c = 0; c < COUT; c++)
                acc[c] = fmaf(v[tap], wc[tap * COUT + c], acc[c]);
    }

    const size_t ob = (((size_t)b * COUT) * OH + oh) * OW + ow;
    const size_t cstride = (size_t)OH * OW;
#pragma unroll
    for (int c = 0; c < COUT; c++) {
        float r = acc[c];
        if (RELU_OUT) r = fmaxf(r, 0.0f);
        out[ob + (size_t)c * cstride] = r;
    }
}

// Final transposed conv (32 -> 1): one thread per half-res position computes
// the 2x2 output quad from its 3x3 neighborhood.
__global__ __launch_bounds__(256) void convt2_quad(
    const float* __restrict__ in,  // (B,32,128,128)
    const float* __restrict__ w,   // (32,1,4,4)
    const float* __restrict__ bias,
    float* __restrict__ out,       // (B,1,256,256)
    int B)
{
    const int IH = 128, IW = 128, CIN = 32, OW = 256;
    const int j = threadIdx.x & 127;
    const int i = (blockIdx.x << 1) + (threadIdx.x >> 7);
    const int b = blockIdx.y;

    const float* __restrict__ inb = in + (size_t)b * CIN * IH * IW;
    const float bz = bias[0];
    float a00 = bz, a01 = bz, a10 = bz, a11 = bz;

    const bool okm = (i > 0);
    const bool okp = (i < IH - 1);
    const bool olm = (j > 0);
    const bool olp = (j < IW - 1);

#pragma unroll 4
    for (int ci = 0; ci < CIN; ci++) {
        const float* __restrict__ p = inb + ((size_t)ci * IH + i) * IW + j;
        const float* __restrict__ wp = w + ci * 16;
        const float vmm = (okm && olm) ? p[-IW - 1] : 0.f;
        const float vm0 = okm ? p[-IW] : 0.f;
        const float vmp = (okm && olp) ? p[-IW + 1] : 0.f;
        const float v0m = olm ? p[-1] : 0.f;
        const float v00 = p[0];
        const float v0p = olp ? p[1] : 0.f;
        const float vpm = (okp && olm) ? p[IW - 1] : 0.f;
        const float vp0 = okp ? p[IW] : 0.f;
        const float vpp = (okp && olp) ? p[IW + 1] : 0.f;
        a00 = fmaf(v00, wp[1 * 4 + 1], a00);
        a00 = fmaf(v0m, wp[1 * 4 + 3], a00);
        a00 = fmaf(vm0, wp[3 * 4 + 1], a00);
        a00 = fmaf(vmm, wp[3 * 4 + 3], a00);
        a01 = fmaf(v0p, wp[1 * 4 + 0], a01);
        a01 = fmaf(v00, wp[1 * 4 + 2], a01);
        a01 = fmaf(vmp, wp[3 * 4 + 0], a01);
        a01 = fmaf(vm0, wp[3 * 4 + 2], a01);
        a10 = fmaf(vp0, wp[0 * 4 + 1], a10);
        a10 = fmaf(vpm, wp[0 * 4 + 3], a10);
        a10 = fmaf(v00, wp[2 * 4 + 1], a10);
        a10 = fmaf(v0m, wp[2 * 4 + 3], a10);
        a11 = fmaf(vpp, wp[0 * 4 + 0], a11);
        a11 = fmaf(vp0, wp[0 * 4 + 2], a11);
        a11 = fmaf(v0p, wp[2 * 4 + 0], a11);
        a11 = fmaf(v00, wp[2 * 4 + 2], a11);
    }

    float* __restrict__ outb = out + (size_t)b * 256 * 256;
    ((float2*)(outb + (size_t)(2 * i) * OW))[j] = make_float2(a00, a01);
    ((float2*)(outb + (size_t)(2 * i + 1) * OW))[j] = make_float2(a10, a11);
}

// Vector quantization: one thread per point (B*HW points, D=64, K=512).
// NOTE: dot product MUST stay a single sequential FMA chain — splitting it
// into partial sums changes rounding and flips argmin (R3 failure).
__global__ __launch_bounds__(256) void vq_kernel(
    const float* __restrict__ h,   // (B,64,HW)
    const float* __restrict__ cb,  // (512,64)
    float* __restrict__ q,         // (B,64,HW)
    int B, int HW)
{
    __shared__ float ee[512];
    for (int k = threadIdx.x; k < 512; k += 256) {
        const float* __restrict__ cp = cb + (size_t)k * 64;
        float s = 0.0f;
#pragma unroll
        for (int i = 0; i < 64; i++) s = fmaf(cp[i], cp[i], s);
        ee[k] = s;
    }
    __syncthreads();

    const int gid = blockIdx.x * 256 + threadIdx.x;
    const int total = B * HW;
    if (gid >= total) return;
    const int hw = gid % HW;
    const int b  = gid / HW;

    const float* __restrict__ hp = h + (size_t)b * 64 * HW + hw;
    float x[64];
#pragma unroll
    for (int i = 0; i < 64; i++) x[i] = hp[(size_t)i * HW];
    float xx = 0.0f;
#pragma unroll
    for (int i = 0; i < 64; i++) xx = fmaf(x[i], x[i], xx);

    float best = 3.402823466e+38f;
    int bidx = 0;
#pragma unroll 2
    for (int k = 0; k < 512; k++) {
        const float* __restrict__ cp = cb + (size_t)k * 64;
        float dot = 0.0f;
#pragma unroll
        for (int i = 0; i < 64; i++) dot = fmaf(x[i], cp[i], dot);
        const float d = xx - 2.0f * dot + ee[k];
        if (d < best) { best = d; bidx = k; }
    }

    const float4* __restrict__ cp4 = (const float4*)(cb + (size_t)bidx * 64);
    float* __restrict__ qp = q + (size_t)b * 64 * HW + hw;
#pragma unroll
    for (int i = 0; i < 16; i++) {
        const float4 v = cp4[i];
        qp[(size_t)(4 * i + 0) * HW] = v.x;
        qp[(size_t)(4 * i + 1) * HW] = v.y;
        qp[(size_t)(4 * i + 2) * HW] = v.z;
        qp[(size_t)(4 * i + 3) * HW] = v.w;
    }
}

extern "C" void kernel_launch(void* const* d_in, const int* in_sizes, int n_in,
                              void* d_out, int out_size, void* d_ws, size_t ws_size,
                              hipStream_t stream) {
    const float* x      = (const float*)d_in[0];
    const float* w_e1   = (const float*)d_in[1];
    const float* b_e1   = (const float*)d_in[2];
    const float* w_e2   = (const float*)d_in[3];
    const float* b_e2   = (const float*)d_in[4];
    const float* w_er1a = (const float*)d_in[5];
    const float* w_er1b = (const float*)d_in[6];
    const float* w_er2a = (const float*)d_in[7];
    const float* w_er2b = (const float*)d_in[8];
    const float* w_pre  = (const float*)d_in[9];
    const float* b_pre  = (const float*)d_in[10];
    const float* cbk    = (const float*)d_in[11];
    const float* w_d1   = (const float*)d_in[12];
    const float* b_d1   = (const float*)d_in[13];
    const float* w_dr1a = (const float*)d_in[14];
    const float* w_dr1b = (const float*)d_in[15];
    const float* w_dr2a = (const float*)d_in[16];
    const float* w_dr2b = (const float*)d_in[17];
    const float* w_t1   = (const float*)d_in[18];
    const float* b_t1   = (const float*)d_in[19];
    const float* w_t2   = (const float*)d_in[20];
    const float* b_t2   = (const float*)d_in[21];
    float* out = (float*)d_out;

    float* A  = (float*)d_ws;            // (32,32,128,128) = 16777216
    float* Bb = A  + 16777216;           // (32,64,64,64)   = 8388608
    float* C  = Bb + 8388608;            // (32,32,64,64)   = 4194304
    float* D  = C  + 4194304;            // (32,64,64,64)   = 8388608
    float* WR = D  + 8388608;            // repacked weights (~189K floats)

    float* r_e1   = WR;                  // 512
    float* r_e2   = r_e1  + 512;         // 32768
    float* r_er1a = r_e2  + 32768;       // 18432
    float* r_er1b = r_er1a + 18432;      // 2048
    float* r_er2a = r_er1b + 2048;       // 18432
    float* r_er2b = r_er2a + 18432;      // 2048
    float* r_pre  = r_er2b + 2048;       // 4096
    float* r_d1   = r_pre  + 4096;       // 36864
    float* r_dr1a = r_d1   + 36864;      // 18432
    float* r_dr1b = r_dr1a + 18432;      // 2048
    float* r_dr2a = r_dr1b + 2048;       // 18432
    float* r_dr2b = r_dr2a + 18432;      // 2048
    float* r_t1   = r_dr2b + 2048;       // 32768

    const dim3 blk(256);
    auto rb = [](int n) { return dim3((n + 255) / 256); };

    // Repack weights (cout innermost)
    repack_w<<<rb(512),   blk, 0, stream>>>(w_e1,   r_e1,   32,  1, 16);
    repack_w<<<rb(32768), blk, 0, stream>>>(w_e2,   r_e2,   64, 32, 16);
    repack_w<<<rb(18432), blk, 0, stream>>>(w_er1a, r_er1a, 32, 64,  9);
    repack_w<<<rb(2048),  blk, 0, stream>>>(w_er1b, r_er1b, 64, 32,  1);
    repack_w<<<rb(18432), blk, 0, stream>>>(w_er2a, r_er2a, 32, 64,  9);
    repack_w<<<rb(2048),  blk, 0, stream>>>(w_er2b, r_er2b, 64, 32,  1);
    repack_w<<<rb(4096),  blk, 0, stream>>>(w_pre,  r_pre,  64, 64,  1);
    repack_w<<<rb(36864), blk, 0, stream>>>(w_d1,   r_d1,   64, 64,  9);
    repack_w<<<rb(18432), blk, 0, stream>>>(w_dr1a, r_dr1a, 32, 64,  9);
    repack_w<<<rb(2048),  blk, 0, stream>>>(w_dr1b, r_dr1b, 64, 32,  1);
    repack_w<<<rb(18432), blk, 0, stream>>>(w_dr2a, r_dr2a, 32, 64,  9);
    repack_w<<<rb(2048),  blk, 0, stream>>>(w_dr2b, r_dr2b, 64, 32,  1);
    repack_t1<<<rb(32768), blk, 0, stream>>>(w_t1, r_t1);

    // Encoder
    conv_direct<1, 32, 32, 4, 2, 1, false, true, false, true>
        <<<dim3(32 * 128 * 128 / 256, 1), blk, 0, stream>>>(
            x, r_e1, b_e1, nullptr, A, 32, 256, 256, 128, 128);
    conv_direct<32, 64, 32, 4, 2, 1, false, true, false, false>
        <<<dim3(32 * 64 * 64 / 256, 2), blk, 0, stream>>>(
            A, r_e2, b_e2, nullptr, Bb, 32, 128, 128, 64, 64);
    conv_direct<64, 32, 32, 3, 1, 1, true, false, false, false>
        <<<dim3(32 * 64 * 64 / 256, 1), blk, 0, stream>>>(
            Bb, r_er1a, nullptr, nullptr, C, 32, 64, 64, 64, 64);
    conv_direct<32, 64, 64, 1, 1, 0, true, false, true, false>
        <<<dim3(32 * 64 * 64 / 256, 1), blk, 0, stream>>>(
            C, r_er1b, nullptr, Bb, Bb, 32, 64, 64, 64, 64);
    conv_direct<64, 32, 32, 3, 1, 1, true, false, false, false>
        <<<dim3(32 * 64 * 64 / 256, 1), blk, 0, stream>>>(
            Bb, r_er2a, nullptr, nullptr, C, 32, 64, 64, 64, 64);
    conv_direct<32, 64, 64, 1, 1, 0, true, false, true, false>
        <<<dim3(32 * 64 * 64 / 256, 1), blk, 0, stream>>>(
            C, r_er2b, nullptr, Bb, Bb, 32, 64, 64, 64, 64);
    conv_direct<64, 64, 64, 1, 1, 0, false, true, false, false>
        <<<dim3(32 * 64 * 64 / 256, 1), blk, 0, stream>>>(
            Bb, r_pre, b_pre, nullptr, D, 32, 64, 64, 64, 64);
    // VQ
    vq_kernel<<<dim3(32 * 4096 / 256), blk, 0, stream>>>(D, cbk, Bb, 32, 4096);
    // Decoder
    conv_direct<64, 64, 32, 3, 1, 1, false, true, false, false>
        <<<dim3(32 * 64 * 64 / 256, 2), blk, 0, stream>>>(
            Bb, r_d1, b_d1, nullptr, D, 32, 64, 64, 64, 64);
    conv_direct<64, 32, 32, 3, 1, 1, true, false, false, false>
        <<<dim3(32 * 64 * 64 / 256, 1), blk, 0, stream>>>(
            D, r_dr1a, nullptr, nullptr, C, 32, 64, 64, 64, 64);
    conv_direct<32, 64, 64, 1, 1, 0, true, false, true, false>
        <<<dim3(32 * 64 * 64 / 256, 1), blk, 0, stream>>>(
            C, r_dr1b, nullptr, D, D, 32, 64, 64, 64, 64);
    conv_direct<64, 32, 32, 3, 1, 1, true, false, false, false>
        <<<dim3(32 * 64 * 64 / 256, 1), blk, 0, stream>>>(
            D, r_dr2a, nullptr, nullptr, C, 32, 64, 64, 64, 64);
    conv_direct<32, 64, 64, 1, 1, 0, true, false, true, false>
        <<<dim3(32 * 64 * 64 / 256, 1), blk, 0, stream>>>(
            C, r_dr2b, nullptr, D, D, 32, 64, 64, 64, 64);
    // t1: D -> A (32,32,128,128), relu
    convt4x4s2<64, 32, true>
        <<<dim3(16, 4, 32), dim3(64, 4, 1), 0, stream>>>(
            D, r_t1, b_t1, A, 32, 64, 64);
    // t2: A -> out (32,1,256,256)
    convt2_quad<<<dim3(64, 32), blk, 0, stream>>>(A, w_t2, b_t2, out, 32);
}